// Round 9
// baseline (297.004 us; speedup 1.0000x reference)
//
#include <hip/hip_runtime.h>

#define NN 100000
#define NE 1600000
#define NB 782          // ceil(NN/128) coarse buckets, 128 nodes each
#define CHUNK 4096
#define CAP 6144        // bsort LDS staging cap (bucket avg ~2046 sigma ~45)
#define LDP 136         // LDS row pitch in bf16 (128 + 8 pad -> 272B, 2-way free)

typedef __attribute__((ext_vector_type(8))) short bf16x8;
typedef __attribute__((ext_vector_type(4))) float f32x4;

static __device__ __forceinline__ unsigned short f2bf(float f) {
  unsigned int u = __float_as_uint(f);
  u += 0x7fff + ((u >> 16) & 1);       // round-to-nearest-even
  return (unsigned short)(u >> 16);
}

// One-time: wt[c][k] = bf16(W[k][c]), combined cols (c<64 -> W_l, c>=64 -> W_r)
__global__ void wprep_k(const float* __restrict__ wl, const float* __restrict__ wr,
                        unsigned short* __restrict__ wt) {
  int i = blockIdx.x * 256 + threadIdx.x;     // 16384
  int c = i >> 7, k = i & 127;
  float v = (c < 64) ? wl[k * 64 + c] : wr[k * 64 + (c - 64)];
  wt[i] = f2bf(v);
}

// MFMA bf16 GEMM, 128-row tiles (r7 proven version: LDS-coalesced staging).
__global__ __launch_bounds__(256) void gemm_mfma(const float* __restrict__ feat,
                                                 const unsigned short* __restrict__ wt,
                                                 float* __restrict__ hl,
                                                 unsigned short* __restrict__ hrb) {
  __shared__ unsigned short ldsA[128][LDP];   // feat tile, bf16 [row][k]
  __shared__ unsigned short ldsB[128][LDP];   // weights  [col][k]
  const int tid = threadIdx.x;
  const int row0 = blockIdx.x * 128;

  for (int idx = tid; idx < 2048; idx += 256) {
    uint4 v = reinterpret_cast<const uint4*>(wt)[idx];
    *reinterpret_cast<uint4*>(&ldsB[idx >> 4][(idx & 15) * 8]) = v;
  }

  for (int it = 0; it < 16; ++it) {
    int r = it * 8 + (tid >> 5);
    int gr = row0 + r;
    int k4 = (tid & 31) * 4;
    float4 v = make_float4(0.f, 0.f, 0.f, 0.f);
    if (gr < NN) v = *reinterpret_cast<const float4*>(&feat[(size_t)gr * 128 + k4]);
    union { unsigned short s[4]; uint2 u; } pk;
    pk.s[0] = f2bf(v.x); pk.s[1] = f2bf(v.y); pk.s[2] = f2bf(v.z); pk.s[3] = f2bf(v.w);
    *reinterpret_cast<uint2*>(&ldsA[r][k4]) = pk.u;
  }
  __syncthreads();

  const int w  = tid >> 6;
  const int ln = tid & 63;
  const int lr = ln & 15;
  const int kb = (ln >> 4) * 8;

  f32x4 acc[2][8];
#pragma unroll
  for (int mt = 0; mt < 2; ++mt)
#pragma unroll
    for (int nt = 0; nt < 8; ++nt) acc[mt][nt] = (f32x4){0.f, 0.f, 0.f, 0.f};

#pragma unroll
  for (int t = 0; t < 4; ++t) {
    const int ko = t * 32 + kb;
    bf16x8 af0 = *reinterpret_cast<const bf16x8*>(&ldsA[w * 32 + lr][ko]);
    bf16x8 af1 = *reinterpret_cast<const bf16x8*>(&ldsA[w * 32 + 16 + lr][ko]);
    bf16x8 bfr[8];
#pragma unroll
    for (int nt = 0; nt < 8; ++nt)
      bfr[nt] = *reinterpret_cast<const bf16x8*>(&ldsB[nt * 16 + lr][ko]);
#pragma unroll
    for (int nt = 0; nt < 8; ++nt) {
      acc[0][nt] = __builtin_amdgcn_mfma_f32_16x16x32_bf16(af0, bfr[nt], acc[0][nt], 0, 0, 0);
      acc[1][nt] = __builtin_amdgcn_mfma_f32_16x16x32_bf16(af1, bfr[nt], acc[1][nt], 0, 0, 0);
    }
  }

#pragma unroll
  for (int mt = 0; mt < 2; ++mt) {
    int rrel = w * 32 + mt * 16 + (ln >> 4) * 4;
#pragma unroll
    for (int q = 0; q < 4; ++q) {
      int gr = row0 + rrel + q;
      if (gr < NN) {
#pragma unroll
        for (int nt = 0; nt < 4; ++nt)       // cols 0..63 -> h_l (f32)
          hl[(size_t)gr * 64 + nt * 16 + lr] = acc[mt][nt][q];
#pragma unroll
        for (int nt = 4; nt < 8; ++nt)       // cols 64..127 -> h_r (bf16)
          hrb[(size_t)gr * 64 + (nt - 4) * 16 + lr] = f2bf(acc[mt][nt][q]);
      }
    }
  }
}

// Phase A: coarse bucket histogram. Global counters padded to 1/cacheline.
__global__ __launch_bounds__(256) void bhist_k(const int* __restrict__ tgt,
                                               int* __restrict__ bcnt) {
  __shared__ int lh[NB];
  const int tid = threadIdx.x;
  const int base = blockIdx.x * CHUNK;
  const int lim = min(CHUNK, NE - base);
  for (int b = tid; b < NB; b += 256) lh[b] = 0;
  __syncthreads();
  for (int i = tid; i < lim; i += 256)
    atomicAdd(&lh[tgt[base + i] >> 7], 1);
  __syncthreads();
  for (int b = tid; b < NB; b += 256)
    if (lh[b]) atomicAdd(&bcnt[b * 16], lh[b]);
}

// Phase B: exclusive scan of bucket counts (single block)
__global__ __launch_bounds__(256) void bscan_k(const int* __restrict__ bcnt,
                                               int* __restrict__ bstart,
                                               int* __restrict__ bcursor) {
  __shared__ int sd[256];
  const int tid = threadIdx.x;
  int v[4]; int s = 0;
#pragma unroll
  for (int j = 0; j < 4; ++j) {
    int idx = tid * 4 + j;
    v[j] = (idx < NB) ? bcnt[idx * 16] : 0;
    s += v[j];
  }
  sd[tid] = s;
  __syncthreads();
  for (int off = 1; off < 256; off <<= 1) {
    int t = (tid >= off) ? sd[tid - off] : 0;
    __syncthreads();
    sd[tid] += t;
    __syncthreads();
  }
  int run = sd[tid] - s;
#pragma unroll
  for (int j = 0; j < 4; ++j) {
    int idx = tid * 4 + j;
    if (idx < NB) { bstart[idx] = run; bcursor[idx * 16] = run; }
    run += v[j];
  }
  if (tid == 255) bstart[NB] = NE;
}

// Phase C: bucket-partition edges. LDS-staged; padded reservation atomics;
// index-parallel bucket-contiguous writeout. rec = (src<<7)|tgt_local.
__global__ __launch_bounds__(256) void bscatter_k(const int* __restrict__ edge,
                                                  int* __restrict__ bcursor,
                                                  int* __restrict__ brec) {
  __shared__ int lcnt[NB];
  __shared__ int lstart[NB];
  __shared__ int gbase[NB];
  __shared__ int lcur[NB];
  __shared__ int srec[CHUNK];
  __shared__ unsigned short bid[CHUNK];
  __shared__ int sd[256];
  const int tid = threadIdx.x;
  const int base = blockIdx.x * CHUNK;
  const int lim = min(CHUNK, NE - base);

  for (int b = tid; b < NB; b += 256) { lcnt[b] = 0; lcur[b] = 0; }
  __syncthreads();
  for (int i = tid; i < lim; i += 256)
    atomicAdd(&lcnt[edge[NE + base + i] >> 7], 1);
  __syncthreads();

  int v[4]; int s = 0;
#pragma unroll
  for (int j = 0; j < 4; ++j) {
    int idx = tid * 4 + j;
    v[j] = (idx < NB) ? lcnt[idx] : 0;
    s += v[j];
  }
  sd[tid] = s;
  __syncthreads();
  for (int off = 1; off < 256; off <<= 1) {
    int t = (tid >= off) ? sd[tid - off] : 0;
    __syncthreads();
    sd[tid] += t;
    __syncthreads();
  }
  int run = sd[tid] - s;
#pragma unroll
  for (int j = 0; j < 4; ++j) {
    int idx = tid * 4 + j;
    if (idx < NB) lstart[idx] = run;
    run += v[j];
  }
  __syncthreads();

  for (int b = tid; b < NB; b += 256)
    if (lcnt[b] > 0) gbase[b] = atomicAdd(&bcursor[b * 16], lcnt[b]);
  __syncthreads();

  for (int i = tid; i < lim; i += 256) {
    int tg = edge[NE + base + i];
    int sr = edge[base + i];
    int b = tg >> 7;
    int r = atomicAdd(&lcur[b], 1);
    int slot = lstart[b] + r;
    srec[slot] = (sr << 7) | (tg & 127);
    bid[slot] = (unsigned short)b;
  }
  __syncthreads();

  for (int i = tid; i < lim; i += 256) {
    int b = bid[i];
    brec[gbase[b] + i - lstart[b]] = srec[i];
  }
}

// Phase D: in-place node-level sort within each bucket; emits start[].
__global__ __launch_bounds__(256) void bsort_k(int* __restrict__ brec,
                                               const int* __restrict__ bstart,
                                               int* __restrict__ start) {
  __shared__ int srec[CAP];
  __shared__ int ncnt[128];
  __shared__ int nst[128];
  __shared__ int sd2[128];
  const int tid = threadIdx.x;
  const int b = blockIdx.x;
  const int s0 = bstart[b];
  const int cnt = bstart[b + 1] - s0;

  if (tid < 128) ncnt[tid] = 0;
  __syncthreads();
  for (int i = tid; i < cnt; i += 256) {
    int r = brec[s0 + i];
    srec[i] = r;
    atomicAdd(&ncnt[r & 127], 1);
  }
  __syncthreads();

  int val = (tid < 128) ? ncnt[tid] : 0;
  if (tid < 128) sd2[tid] = val;
  __syncthreads();
  for (int off = 1; off < 128; off <<= 1) {
    int t = 0;
    if (tid < 128 && tid >= off) t = sd2[tid - off];
    __syncthreads();
    if (tid < 128) sd2[tid] += t;
    __syncthreads();
  }
  if (tid < 128) {
    nst[tid] = sd2[tid] - val;
    int nid = (b << 7) + tid;
    if (nid < NN) start[nid] = s0 + nst[tid];
    ncnt[tid] = 0;                       // reuse as cursor
  }
  if (b == NB - 1 && tid == 0) start[NN] = NE;
  __syncthreads();

  for (int i = tid; i < cnt; i += 256) {
    int r = srec[i];
    int tl = r & 127;
    int p = atomicAdd(&ncnt[tl], 1);
    brec[s0 + nst[tl] + p] = r >> 7;     // final: grouped src ids
  }
}

#define UNPK(D_, U0_, U1_)                             \
  D_.x = __uint_as_float((U0_) << 16);                 \
  D_.y = __uint_as_float((U0_) & 0xffff0000u);         \
  D_.z = __uint_as_float((U1_) << 16);                 \
  D_.w = __uint_as_float((U1_) & 0xffff0000u);

#define LKY(Z_, XI_, X_)                                          \
  Z_.x = XI_.x + X_.x; Z_.y = XI_.y + X_.y;                       \
  Z_.z = XI_.z + X_.z; Z_.w = XI_.w + X_.w;                       \
  Z_.x = fmaxf(Z_.x, 0.2f * Z_.x); Z_.y = fmaxf(Z_.y, 0.2f * Z_.y); \
  Z_.z = fmaxf(Z_.z, 0.2f * Z_.z); Z_.w = fmaxf(Z_.w, 0.2f * Z_.w);

#define DOT(T_, Z_, A_)                                \
  T_ = fmaf(Z_.x, A_.x, T_); T_ = fmaf(Z_.y, A_.y, T_); \
  T_ = fmaf(Z_.z, A_.z, T_); T_ = fmaf(Z_.w, A_.w, T_);

#define ACC(AC_, E_, X_)                               \
  AC_.x = fmaf(E_, X_.x, AC_.x); AC_.y = fmaf(E_, X_.y, AC_.y); \
  AC_.z = fmaf(E_, X_.z, AC_.z); AC_.w = fmaf(E_, X_.w, AC_.w);

#define RED(V_, M_)                                    \
  V_.x += __shfl_xor(V_.x, M_); V_.y += __shfl_xor(V_.y, M_); \
  V_.z += __shfl_xor(V_.z, M_); V_.w += __shfl_xor(V_.w, M_);

// One wave per node; 4 lanes per edge (lane&3 = head, lane holds all 16
// features of its head), 16 edges per wave-step. Zero in-loop shuffles:
// head dot is in-lane; cross-slot reduce once per node in epilogue.
__global__ __launch_bounds__(256) void node_k(const float* __restrict__ hl,
                                              const unsigned short* __restrict__ hrb,
                                              const int* __restrict__ ssrc,
                                              const int* __restrict__ start,
                                              const float* __restrict__ att,
                                              const float* __restrict__ bias,
                                              float* __restrict__ out) {
  const int lane = threadIdx.x & 63;
  const int n  = blockIdx.x * 4 + (threadIdx.x >> 6);
  const int g  = lane >> 2;          // edge slot 0..15
  const int h  = lane & 3;           // head
  const int ho = h * 16;             // feature offset of this head

  const float4* xiq = reinterpret_cast<const float4*>(hl + (size_t)n * 64 + ho);
  const float4 xi0 = xiq[0], xi1 = xiq[1], xi2 = xiq[2], xi3 = xiq[3];
  const float4* aq = reinterpret_cast<const float4*>(att + ho);
  const float4 a0 = aq[0], a1 = aq[1], a2 = aq[2], a3 = aq[3];

  const int s = start[n];
  const int e = start[n + 1];
  const unsigned short* __restrict__ hrp = hrb + ho;

  float  den = 0.f;
  float4 acc0 = make_float4(0.f, 0.f, 0.f, 0.f);
  float4 acc1 = acc0, acc2 = acc0, acc3 = acc0;

  for (int i = s; i < e; i += 16) {
    int r = i + g;
    bool valid = r < e;
    int j = ssrc[valid ? r : s];
    const uint4* p = reinterpret_cast<const uint4*>(hrp + (size_t)j * 64);
    uint4 q0 = p[0];                  // feats 0..7 of this head
    uint4 q1 = p[1];                  // feats 8..15

    float4 x0, x1, x2, x3;
    UNPK(x0, q0.x, q0.y); UNPK(x1, q0.z, q0.w);
    UNPK(x2, q1.x, q1.y); UNPK(x3, q1.z, q1.w);

    float4 z;
    float t = 0.f;
    LKY(z, xi0, x0); DOT(t, z, a0);
    LKY(z, xi1, x1); DOT(t, z, a1);
    LKY(z, xi2, x2); DOT(t, z, a2);
    LKY(z, xi3, x3); DOT(t, z, a3);

    float ex = valid ? __expf(t) : 0.f;   // no max-shift needed (|score| << 88)
    den += ex;
    ACC(acc0, ex, x0); ACC(acc1, ex, x1);
    ACC(acc2, ex, x2); ACC(acc3, ex, x3);
  }

  // reduce across the 16 edge slots (lanes sharing the same head)
#pragma unroll
  for (int m = 4; m <= 32; m <<= 1) {
    den += __shfl_xor(den, m);
    RED(acc0, m); RED(acc1, m); RED(acc2, m); RED(acc3, m);
  }

  if (g == 0) {
    float inv = (e > s) ? 1.f / den : 0.f;   // deg==0 -> bias only
    const float4* bq = reinterpret_cast<const float4*>(bias + ho);
    float4* oq = reinterpret_cast<float4*>(out + (size_t)n * 64 + ho);
    float4 b, r;
    b = bq[0]; r.x = fmaf(acc0.x, inv, b.x); r.y = fmaf(acc0.y, inv, b.y);
    r.z = fmaf(acc0.z, inv, b.z); r.w = fmaf(acc0.w, inv, b.w); oq[0] = r;
    b = bq[1]; r.x = fmaf(acc1.x, inv, b.x); r.y = fmaf(acc1.y, inv, b.y);
    r.z = fmaf(acc1.z, inv, b.z); r.w = fmaf(acc1.w, inv, b.w); oq[1] = r;
    b = bq[2]; r.x = fmaf(acc2.x, inv, b.x); r.y = fmaf(acc2.y, inv, b.y);
    r.z = fmaf(acc2.z, inv, b.z); r.w = fmaf(acc2.w, inv, b.w); oq[2] = r;
    b = bq[3]; r.x = fmaf(acc3.x, inv, b.x); r.y = fmaf(acc3.y, inv, b.y);
    r.z = fmaf(acc3.z, inv, b.z); r.w = fmaf(acc3.w, inv, b.w); oq[3] = r;
  }
}

extern "C" void kernel_launch(void* const* d_in, const int* in_sizes, int n_in,
                              void* d_out, int out_size, void* d_ws, size_t ws_size,
                              hipStream_t stream) {
  const float* feat = (const float*)d_in[0];
  const int*   edge = (const int*)d_in[1];
  const float* wl   = (const float*)d_in[2];
  const float* wr   = (const float*)d_in[3];
  const float* att  = (const float*)d_in[4];
  const float* bias = (const float*)d_in[5];
  float* out = (float*)d_out;

  // workspace layout (~45.6 MB)
  float* hl       = (float*)d_ws;                        // NN*64 f32
  unsigned short* hrb = (unsigned short*)(hl + (size_t)NN * 64);  // NN*64 bf16
  int*   brec     = (int*)(hrb + (size_t)NN * 64);       // NE
  int*   bcnt     = brec + NE;                           // NB*16 (padded, 1/line)
  int*   bstart   = bcnt + NB * 16;                      // NB+1
  int*   bcursor  = bstart + NB + 1;                     // NB*16 (padded)
  int*   start    = bcursor + NB * 16;                   // NN+1
  unsigned short* wt = (unsigned short*)(start + NN + 1);  // 16384 bf16

  (void)hipMemsetAsync(bcnt, 0, NB * 16 * sizeof(int), stream);

  const int nchunk = (NE + CHUNK - 1) / CHUNK;           // 391
  wprep_k<<<64, 256, 0, stream>>>(wl, wr, wt);
  gemm_mfma<<<(NN + 127) / 128, 256, 0, stream>>>(feat, wt, hl, hrb);
  bhist_k<<<nchunk, 256, 0, stream>>>(edge + NE, bcnt);
  bscan_k<<<1, 256, 0, stream>>>(bcnt, bstart, bcursor);
  bscatter_k<<<nchunk, 256, 0, stream>>>(edge, bcursor, brec);
  bsort_k<<<NB, 256, 0, stream>>>(brec, bstart, start);
  node_k<<<NN / 4, 256, 0, stream>>>(hl, hrb, brec, start, att, bias, out);
}

// Round 10
// 223.197 us; speedup vs baseline: 1.3307x; 1.3307x over previous
//
#include <hip/hip_runtime.h>

#define NN 100000
#define NE 1600000
#define NB 782          // ceil(NN/128) coarse buckets, 128 nodes each
#define CHUNK 4096
#define BCAP 2560       // padded bucket capacity (mean 2048, sigma ~45 -> 11 sigma)
#define LDP 136         // LDS row pitch in bf16 (128 + 8 pad -> 272B, 2-way free)

typedef __attribute__((ext_vector_type(8))) short bf16x8;
typedef __attribute__((ext_vector_type(4))) float f32x4;

static __device__ __forceinline__ unsigned short f2bf(float f) {
  unsigned int u = __float_as_uint(f);
  u += 0x7fff + ((u >> 16) & 1);       // round-to-nearest-even
  return (unsigned short)(u >> 16);
}

// One-time: wt[c][k] = bf16(W[k][c]) (c<64 -> W_l, c>=64 -> W_r) + bucket cursor init
__global__ void wprep_k(const float* __restrict__ wl, const float* __restrict__ wr,
                        unsigned short* __restrict__ wt, int* __restrict__ bcursor) {
  int i = blockIdx.x * 256 + threadIdx.x;     // 16384
  int c = i >> 7, k = i & 127;
  float v = (c < 64) ? wl[k * 64 + c] : wr[k * 64 + (c - 64)];
  wt[i] = f2bf(v);
  if (i < NB) bcursor[i * 16] = i * BCAP;     // padded-region base
}

// MFMA bf16 GEMM, 128-row tiles (r7 proven version: LDS-coalesced staging).
__global__ __launch_bounds__(256) void gemm_mfma(const float* __restrict__ feat,
                                                 const unsigned short* __restrict__ wt,
                                                 float* __restrict__ hl,
                                                 unsigned short* __restrict__ hrb) {
  __shared__ unsigned short ldsA[128][LDP];   // feat tile, bf16 [row][k]
  __shared__ unsigned short ldsB[128][LDP];   // weights  [col][k]
  const int tid = threadIdx.x;
  const int row0 = blockIdx.x * 128;

  for (int idx = tid; idx < 2048; idx += 256) {
    uint4 v = reinterpret_cast<const uint4*>(wt)[idx];
    *reinterpret_cast<uint4*>(&ldsB[idx >> 4][(idx & 15) * 8]) = v;
  }

  for (int it = 0; it < 16; ++it) {
    int r = it * 8 + (tid >> 5);
    int gr = row0 + r;
    int k4 = (tid & 31) * 4;
    float4 v = make_float4(0.f, 0.f, 0.f, 0.f);
    if (gr < NN) v = *reinterpret_cast<const float4*>(&feat[(size_t)gr * 128 + k4]);
    union { unsigned short s[4]; uint2 u; } pk;
    pk.s[0] = f2bf(v.x); pk.s[1] = f2bf(v.y); pk.s[2] = f2bf(v.z); pk.s[3] = f2bf(v.w);
    *reinterpret_cast<uint2*>(&ldsA[r][k4]) = pk.u;
  }
  __syncthreads();

  const int w  = tid >> 6;
  const int ln = tid & 63;
  const int lr = ln & 15;
  const int kb = (ln >> 4) * 8;

  f32x4 acc[2][8];
#pragma unroll
  for (int mt = 0; mt < 2; ++mt)
#pragma unroll
    for (int nt = 0; nt < 8; ++nt) acc[mt][nt] = (f32x4){0.f, 0.f, 0.f, 0.f};

#pragma unroll
  for (int t = 0; t < 4; ++t) {
    const int ko = t * 32 + kb;
    bf16x8 af0 = *reinterpret_cast<const bf16x8*>(&ldsA[w * 32 + lr][ko]);
    bf16x8 af1 = *reinterpret_cast<const bf16x8*>(&ldsA[w * 32 + 16 + lr][ko]);
    bf16x8 bfr[8];
#pragma unroll
    for (int nt = 0; nt < 8; ++nt)
      bfr[nt] = *reinterpret_cast<const bf16x8*>(&ldsB[nt * 16 + lr][ko]);
#pragma unroll
    for (int nt = 0; nt < 8; ++nt) {
      acc[0][nt] = __builtin_amdgcn_mfma_f32_16x16x32_bf16(af0, bfr[nt], acc[0][nt], 0, 0, 0);
      acc[1][nt] = __builtin_amdgcn_mfma_f32_16x16x32_bf16(af1, bfr[nt], acc[1][nt], 0, 0, 0);
    }
  }

#pragma unroll
  for (int mt = 0; mt < 2; ++mt) {
    int rrel = w * 32 + mt * 16 + (ln >> 4) * 4;
#pragma unroll
    for (int q = 0; q < 4; ++q) {
      int gr = row0 + rrel + q;
      if (gr < NN) {
#pragma unroll
        for (int nt = 0; nt < 4; ++nt)       // cols 0..63 -> h_l (f32)
          hl[(size_t)gr * 64 + nt * 16 + lr] = acc[mt][nt][q];
#pragma unroll
        for (int nt = 4; nt < 8; ++nt)       // cols 64..127 -> h_r (bf16)
          hrb[(size_t)gr * 64 + (nt - 4) * 16 + lr] = f2bf(acc[mt][nt][q]);
      }
    }
  }
}

// Bucket-partition edges into fixed padded regions (bucket b owns
// [b*BCAP, (b+1)*BCAP)). No global histogram/scan needed. LDS-staged so
// global writes are bucket-contiguous runs. rec = (src<<7)|tgt_local.
__global__ __launch_bounds__(256) void bscatter_k(const int* __restrict__ edge,
                                                  int* __restrict__ bcursor,
                                                  int* __restrict__ brec) {
  __shared__ int lcnt[NB];
  __shared__ int lstart[NB];
  __shared__ int gbase[NB];
  __shared__ int lcur[NB];
  __shared__ int srec[CHUNK];
  __shared__ unsigned short bid[CHUNK];
  __shared__ int sd[256];
  const int tid = threadIdx.x;
  const int base = blockIdx.x * CHUNK;
  const int lim = min(CHUNK, NE - base);

  for (int b = tid; b < NB; b += 256) { lcnt[b] = 0; lcur[b] = 0; }
  __syncthreads();
  for (int i = tid; i < lim; i += 256)
    atomicAdd(&lcnt[edge[NE + base + i] >> 7], 1);
  __syncthreads();

  int v[4]; int s = 0;
#pragma unroll
  for (int j = 0; j < 4; ++j) {
    int idx = tid * 4 + j;
    v[j] = (idx < NB) ? lcnt[idx] : 0;
    s += v[j];
  }
  sd[tid] = s;
  __syncthreads();
  for (int off = 1; off < 256; off <<= 1) {
    int t = (tid >= off) ? sd[tid - off] : 0;
    __syncthreads();
    sd[tid] += t;
    __syncthreads();
  }
  int run = sd[tid] - s;
#pragma unroll
  for (int j = 0; j < 4; ++j) {
    int idx = tid * 4 + j;
    if (idx < NB) lstart[idx] = run;
    run += v[j];
  }
  __syncthreads();

  // reserve space in the bucket's padded region (padded cursors, 1/line)
  for (int b = tid; b < NB; b += 256)
    if (lcnt[b] > 0) gbase[b] = atomicAdd(&bcursor[b * 16], lcnt[b]);
  __syncthreads();

  for (int i = tid; i < lim; i += 256) {
    int tg = edge[NE + base + i];
    int sr = edge[base + i];
    int b = tg >> 7;
    int r = atomicAdd(&lcur[b], 1);
    int slot = lstart[b] + r;
    srec[slot] = (sr << 7) | (tg & 127);
    bid[slot] = (unsigned short)b;
  }
  __syncthreads();

  for (int i = tid; i < lim; i += 256) {
    int b = bid[i];
    brec[gbase[b] + i - lstart[b]] = srec[i];
  }
}

// Node-level sort within each padded bucket; emits absolute (start,end) per node.
__global__ __launch_bounds__(256) void bsort_k(int* __restrict__ brec,
                                               const int* __restrict__ bcursor,
                                               int2* __restrict__ srange) {
  __shared__ int srec[BCAP];
  __shared__ int ncnt[128];
  __shared__ int nst[128];
  __shared__ int sd2[128];
  const int tid = threadIdx.x;
  const int b = blockIdx.x;
  const int s0 = b * BCAP;
  const int cnt = bcursor[b * 16] - s0;

  if (tid < 128) ncnt[tid] = 0;
  __syncthreads();
  for (int i = tid; i < cnt; i += 256) {
    int r = brec[s0 + i];
    srec[i] = r;
    atomicAdd(&ncnt[r & 127], 1);
  }
  __syncthreads();

  int val = (tid < 128) ? ncnt[tid] : 0;
  if (tid < 128) sd2[tid] = val;
  __syncthreads();
  for (int off = 1; off < 128; off <<= 1) {
    int t = 0;
    if (tid < 128 && tid >= off) t = sd2[tid - off];
    __syncthreads();
    if (tid < 128) sd2[tid] += t;
    __syncthreads();
  }
  if (tid < 128) {
    int st = sd2[tid] - val;
    nst[tid] = st;
    int nid = (b << 7) + tid;
    if (nid < NN) srange[nid] = make_int2(s0 + st, s0 + st + val);
    ncnt[tid] = 0;                       // reuse as cursor
  }
  __syncthreads();

  for (int i = tid; i < cnt; i += 256) {
    int r = srec[i];
    int tl = r & 127;
    int p = atomicAdd(&ncnt[tl], 1);
    brec[s0 + nst[tl] + p] = r >> 7;     // final: grouped src ids
  }
}

#define UNPK(D_, U0_, U1_)                             \
  D_.x = __uint_as_float((U0_) << 16);                 \
  D_.y = __uint_as_float((U0_) & 0xffff0000u);         \
  D_.z = __uint_as_float((U1_) << 16);                 \
  D_.w = __uint_as_float((U1_) & 0xffff0000u);

#define ACC(AC_, E_, X_)                               \
  AC_.x = fmaf(E_, X_.x, AC_.x); AC_.y = fmaf(E_, X_.y, AC_.y); \
  AC_.z = fmaf(E_, X_.z, AC_.z); AC_.w = fmaf(E_, X_.w, AC_.w);

// One wave per node; 16 lanes per edge (4 heads x float4), 16 edges in flight
// (r7 proven layout, unroll deepened 2->4). h_r gathered as bf16.
__global__ __launch_bounds__(256) void node_k(const float* __restrict__ hl,
                                              const unsigned short* __restrict__ hrb,
                                              const int* __restrict__ ssrc,
                                              const int2* __restrict__ srange,
                                              const float* __restrict__ att,
                                              const float* __restrict__ bias,
                                              float* __restrict__ out) {
  const int lane = threadIdx.x & 63;
  const int n  = blockIdx.x * 4 + (threadIdx.x >> 6);
  const int g  = lane >> 4;          // edge slot 0..3
  const int fo = (lane & 15) * 4;    // (head,feature-quad) offset within 64

  const float4 xi = *reinterpret_cast<const float4*>(hl + (size_t)n * 64 + fo);
  const float4 a  = *reinterpret_cast<const float4*>(att + fo);
  const int2 se = srange[n];
  const int s = se.x, e = se.y;
  const unsigned short* __restrict__ hrp = hrb + fo;

  float  den = 0.f;
  float4 acc = make_float4(0.f, 0.f, 0.f, 0.f);

  for (int i = s; i < e; i += 16) {
    uint2 p[4];
    bool  v[4];
#pragma unroll
    for (int u = 0; u < 4; ++u) {      // 4 independent gathers in flight
      int r = i + u * 4 + g;
      v[u] = r < e;
      int j = ssrc[v[u] ? r : s];
      p[u] = *reinterpret_cast<const uint2*>(hrp + (size_t)j * 64);
    }
#pragma unroll
    for (int u = 0; u < 4; ++u) {
      float4 x;
      UNPK(x, p[u].x, p[u].y);
      float4 z;
      z.x = xi.x + x.x; z.y = xi.y + x.y; z.z = xi.z + x.z; z.w = xi.w + x.w;
      z.x = fmaxf(z.x, 0.2f * z.x); z.y = fmaxf(z.y, 0.2f * z.y);
      z.z = fmaxf(z.z, 0.2f * z.z); z.w = fmaxf(z.w, 0.2f * z.w);
      float t = z.x * a.x;
      t = fmaf(z.y, a.y, t); t = fmaf(z.z, a.z, t); t = fmaf(z.w, a.w, t);
      t += __shfl_xor(t, 1); t += __shfl_xor(t, 2);   // per-head dot (4 lanes)
      float ex = v[u] ? __expf(t) : 0.f;              // |score| << 88: no max-shift
      den += ex;
      ACC(acc, ex, x);
    }
  }

  // reduce across the 4 edge slots
#pragma unroll
  for (int m = 16; m <= 32; m <<= 1) {
    den   += __shfl_xor(den, m);
    acc.x += __shfl_xor(acc.x, m);
    acc.y += __shfl_xor(acc.y, m);
    acc.z += __shfl_xor(acc.z, m);
    acc.w += __shfl_xor(acc.w, m);
  }

  if (g == 0) {
    float inv = (e > s) ? 1.f / den : 0.f;   // deg==0 -> bias only
    float4 b4 = *reinterpret_cast<const float4*>(bias + fo);
    float4 r;
    r.x = fmaf(acc.x, inv, b4.x);
    r.y = fmaf(acc.y, inv, b4.y);
    r.z = fmaf(acc.z, inv, b4.z);
    r.w = fmaf(acc.w, inv, b4.w);
    *reinterpret_cast<float4*>(out + (size_t)n * 64 + fo) = r;
  }
}

extern "C" void kernel_launch(void* const* d_in, const int* in_sizes, int n_in,
                              void* d_out, int out_size, void* d_ws, size_t ws_size,
                              hipStream_t stream) {
  const float* feat = (const float*)d_in[0];
  const int*   edge = (const int*)d_in[1];
  const float* wl   = (const float*)d_in[2];
  const float* wr   = (const float*)d_in[3];
  const float* att  = (const float*)d_in[4];
  const float* bias = (const float*)d_in[5];
  float* out = (float*)d_out;

  // workspace layout (~47.5 MB)
  float* hl       = (float*)d_ws;                        // NN*64 f32
  unsigned short* hrb = (unsigned short*)(hl + (size_t)NN * 64);  // NN*64 bf16
  int*   brec     = (int*)(hrb + (size_t)NN * 64);       // NB*BCAP (padded buckets)
  int*   bcursor  = brec + (size_t)NB * BCAP;            // NB*16 (padded, 1/line)
  int2*  srange   = (int2*)(bcursor + NB * 16);          // NN int2
  unsigned short* wt = (unsigned short*)(srange + NN);   // 16384 bf16

  const int nchunk = (NE + CHUNK - 1) / CHUNK;           // 391
  wprep_k<<<64, 256, 0, stream>>>(wl, wr, wt, bcursor);
  gemm_mfma<<<(NN + 127) / 128, 256, 0, stream>>>(feat, wt, hl, hrb);
  bscatter_k<<<nchunk, 256, 0, stream>>>(edge, bcursor, brec);
  bsort_k<<<NB, 256, 0, stream>>>(brec, bcursor, srange);
  node_k<<<NN / 4, 256, 0, stream>>>(hl, hrb, brec, srange, att, bias, out);
}

// Round 11
// 222.377 us; speedup vs baseline: 1.3356x; 1.0037x over previous
//
#include <hip/hip_runtime.h>

#define NN 100000
#define NE 1600000
#define NB 782          // ceil(NN/128) coarse buckets, 128 nodes each
#define CHUNK 4096
#define BCAP 2560       // padded bucket capacity (mean 2048, sigma ~45 -> 11 sigma)
#define LDP 136         // LDS row pitch in bf16 (128 + 8 pad -> 272B, 2-way free)

typedef __attribute__((ext_vector_type(8))) short bf16x8;
typedef __attribute__((ext_vector_type(4))) float f32x4;
typedef __attribute__((ext_vector_type(2))) float f32x2;

static __device__ __forceinline__ unsigned short f2bf(float f) {
  unsigned int u = __float_as_uint(f);
  u += 0x7fff + ((u >> 16) & 1);       // round-to-nearest-even
  return (unsigned short)(u >> 16);
}

static __device__ __forceinline__ f32x2 unpk2(unsigned int u) {
  f32x2 r;
  r.x = __uint_as_float(u << 16);
  r.y = __uint_as_float(u & 0xffff0000u);
  return r;
}

// One-time: wt[c][k] = bf16(W[k][c]) (c<64 -> W_l, c>=64 -> W_r) + bucket cursor init
__global__ void wprep_k(const float* __restrict__ wl, const float* __restrict__ wr,
                        unsigned short* __restrict__ wt, int* __restrict__ bcursor) {
  int i = blockIdx.x * 256 + threadIdx.x;     // 16384
  int c = i >> 7, k = i & 127;
  float v = (c < 64) ? wl[k * 64 + c] : wr[k * 64 + (c - 64)];
  wt[i] = f2bf(v);
  if (i < NB) bcursor[i * 16] = i * BCAP;     // padded-region base
}

// MFMA bf16 GEMM, 128-row tiles (r7 proven version: LDS-coalesced staging).
__global__ __launch_bounds__(256) void gemm_mfma(const float* __restrict__ feat,
                                                 const unsigned short* __restrict__ wt,
                                                 float* __restrict__ hl,
                                                 unsigned short* __restrict__ hrb) {
  __shared__ unsigned short ldsA[128][LDP];   // feat tile, bf16 [row][k]
  __shared__ unsigned short ldsB[128][LDP];   // weights  [col][k]
  const int tid = threadIdx.x;
  const int row0 = blockIdx.x * 128;

  for (int idx = tid; idx < 2048; idx += 256) {
    uint4 v = reinterpret_cast<const uint4*>(wt)[idx];
    *reinterpret_cast<uint4*>(&ldsB[idx >> 4][(idx & 15) * 8]) = v;
  }

  for (int it = 0; it < 16; ++it) {
    int r = it * 8 + (tid >> 5);
    int gr = row0 + r;
    int k4 = (tid & 31) * 4;
    float4 v = make_float4(0.f, 0.f, 0.f, 0.f);
    if (gr < NN) v = *reinterpret_cast<const float4*>(&feat[(size_t)gr * 128 + k4]);
    union { unsigned short s[4]; uint2 u; } pk;
    pk.s[0] = f2bf(v.x); pk.s[1] = f2bf(v.y); pk.s[2] = f2bf(v.z); pk.s[3] = f2bf(v.w);
    *reinterpret_cast<uint2*>(&ldsA[r][k4]) = pk.u;
  }
  __syncthreads();

  const int w  = tid >> 6;
  const int ln = tid & 63;
  const int lr = ln & 15;
  const int kb = (ln >> 4) * 8;

  f32x4 acc[2][8];
#pragma unroll
  for (int mt = 0; mt < 2; ++mt)
#pragma unroll
    for (int nt = 0; nt < 8; ++nt) acc[mt][nt] = (f32x4){0.f, 0.f, 0.f, 0.f};

#pragma unroll
  for (int t = 0; t < 4; ++t) {
    const int ko = t * 32 + kb;
    bf16x8 af0 = *reinterpret_cast<const bf16x8*>(&ldsA[w * 32 + lr][ko]);
    bf16x8 af1 = *reinterpret_cast<const bf16x8*>(&ldsA[w * 32 + 16 + lr][ko]);
    bf16x8 bfr[8];
#pragma unroll
    for (int nt = 0; nt < 8; ++nt)
      bfr[nt] = *reinterpret_cast<const bf16x8*>(&ldsB[nt * 16 + lr][ko]);
#pragma unroll
    for (int nt = 0; nt < 8; ++nt) {
      acc[0][nt] = __builtin_amdgcn_mfma_f32_16x16x32_bf16(af0, bfr[nt], acc[0][nt], 0, 0, 0);
      acc[1][nt] = __builtin_amdgcn_mfma_f32_16x16x32_bf16(af1, bfr[nt], acc[1][nt], 0, 0, 0);
    }
  }

#pragma unroll
  for (int mt = 0; mt < 2; ++mt) {
    int rrel = w * 32 + mt * 16 + (ln >> 4) * 4;
#pragma unroll
    for (int q = 0; q < 4; ++q) {
      int gr = row0 + rrel + q;
      if (gr < NN) {
#pragma unroll
        for (int nt = 0; nt < 4; ++nt)       // cols 0..63 -> h_l (f32)
          hl[(size_t)gr * 64 + nt * 16 + lr] = acc[mt][nt][q];
#pragma unroll
        for (int nt = 4; nt < 8; ++nt)       // cols 64..127 -> h_r (bf16)
          hrb[(size_t)gr * 64 + (nt - 4) * 16 + lr] = f2bf(acc[mt][nt][q]);
      }
    }
  }
}

// Bucket-partition edges into fixed padded regions (bucket b owns
// [b*BCAP, (b+1)*BCAP)). LDS-staged; padded reservation atomics;
// index-parallel bucket-contiguous writeout. rec = (src<<7)|tgt_local.
__global__ __launch_bounds__(256) void bscatter_k(const int* __restrict__ edge,
                                                  int* __restrict__ bcursor,
                                                  int* __restrict__ brec) {
  __shared__ int lcnt[NB];
  __shared__ int lstart[NB];
  __shared__ int gbase[NB];
  __shared__ int lcur[NB];
  __shared__ int srec[CHUNK];
  __shared__ unsigned short bid[CHUNK];
  __shared__ int sd[256];
  const int tid = threadIdx.x;
  const int base = blockIdx.x * CHUNK;
  const int lim = min(CHUNK, NE - base);

  for (int b = tid; b < NB; b += 256) { lcnt[b] = 0; lcur[b] = 0; }
  __syncthreads();
  for (int i = tid; i < lim; i += 256)
    atomicAdd(&lcnt[edge[NE + base + i] >> 7], 1);
  __syncthreads();

  int v[4]; int s = 0;
#pragma unroll
  for (int j = 0; j < 4; ++j) {
    int idx = tid * 4 + j;
    v[j] = (idx < NB) ? lcnt[idx] : 0;
    s += v[j];
  }
  sd[tid] = s;
  __syncthreads();
  for (int off = 1; off < 256; off <<= 1) {
    int t = (tid >= off) ? sd[tid - off] : 0;
    __syncthreads();
    sd[tid] += t;
    __syncthreads();
  }
  int run = sd[tid] - s;
#pragma unroll
  for (int j = 0; j < 4; ++j) {
    int idx = tid * 4 + j;
    if (idx < NB) lstart[idx] = run;
    run += v[j];
  }
  __syncthreads();

  for (int b = tid; b < NB; b += 256)
    if (lcnt[b] > 0) gbase[b] = atomicAdd(&bcursor[b * 16], lcnt[b]);
  __syncthreads();

  for (int i = tid; i < lim; i += 256) {
    int tg = edge[NE + base + i];
    int sr = edge[base + i];
    int b = tg >> 7;
    int r = atomicAdd(&lcur[b], 1);
    int slot = lstart[b] + r;
    srec[slot] = (sr << 7) | (tg & 127);
    bid[slot] = (unsigned short)b;
  }
  __syncthreads();

  for (int i = tid; i < lim; i += 256) {
    int b = bid[i];
    brec[gbase[b] + i - lstart[b]] = srec[i];
  }
}

// Node-level sort within each padded bucket; emits absolute (start,end) per node.
__global__ __launch_bounds__(256) void bsort_k(int* __restrict__ brec,
                                               const int* __restrict__ bcursor,
                                               int2* __restrict__ srange) {
  __shared__ int srec[BCAP];
  __shared__ int ncnt[128];
  __shared__ int nst[128];
  __shared__ int sd2[128];
  const int tid = threadIdx.x;
  const int b = blockIdx.x;
  const int s0 = b * BCAP;
  const int cnt = bcursor[b * 16] - s0;

  if (tid < 128) ncnt[tid] = 0;
  __syncthreads();
  for (int i = tid; i < cnt; i += 256) {
    int r = brec[s0 + i];
    srec[i] = r;
    atomicAdd(&ncnt[r & 127], 1);
  }
  __syncthreads();

  int val = (tid < 128) ? ncnt[tid] : 0;
  if (tid < 128) sd2[tid] = val;
  __syncthreads();
  for (int off = 1; off < 128; off <<= 1) {
    int t = 0;
    if (tid < 128 && tid >= off) t = sd2[tid - off];
    __syncthreads();
    if (tid < 128) sd2[tid] += t;
    __syncthreads();
  }
  if (tid < 128) {
    int st = sd2[tid] - val;
    nst[tid] = st;
    int nid = (b << 7) + tid;
    if (nid < NN) srange[nid] = make_int2(s0 + st, s0 + st + val);
    ncnt[tid] = 0;                       // reuse as cursor
  }
  __syncthreads();

  for (int i = tid; i < cnt; i += 256) {
    int r = srec[i];
    int tl = r & 127;
    int p = atomicAdd(&ncnt[tl], 1);
    brec[s0 + nst[tl] + p] = r >> 7;     // final: grouped src ids
  }
}

// One wave per node; 16 lanes per edge (4 heads x float4), 16 edges in flight.
// Inner math as float2 vector ops -> v_pk_{add,mul,max,fma}_f32 (2 floats/instr).
__global__ __launch_bounds__(256) void node_k(const float* __restrict__ hl,
                                              const unsigned short* __restrict__ hrb,
                                              const int* __restrict__ ssrc,
                                              const int2* __restrict__ srange,
                                              const float* __restrict__ att,
                                              const float* __restrict__ bias,
                                              float* __restrict__ out) {
  const int lane = threadIdx.x & 63;
  const int n  = blockIdx.x * 4 + (threadIdx.x >> 6);
  const int g  = lane >> 4;          // edge slot 0..3
  const int fo = (lane & 15) * 4;    // (head,feature-quad) offset within 64

  const float4 xiq = *reinterpret_cast<const float4*>(hl + (size_t)n * 64 + fo);
  const float4 aq  = *reinterpret_cast<const float4*>(att + fo);
  f32x2 xi01, xi23, a01, a23;
  xi01.x = xiq.x; xi01.y = xiq.y; xi23.x = xiq.z; xi23.y = xiq.w;
  a01.x  = aq.x;  a01.y  = aq.y;  a23.x  = aq.z;  a23.y  = aq.w;

  const int2 se = srange[n];
  const int s = se.x, e = se.y;
  const unsigned short* __restrict__ hrp = hrb + fo;

  float den = 0.f;
  f32x2 acc01 = (f32x2)0.f, acc23 = (f32x2)0.f;

  for (int i = s; i < e; i += 16) {
    uint2 p[4];
    bool  v[4];
#pragma unroll
    for (int u = 0; u < 4; ++u) {      // 4 independent gathers in flight
      int r = i + u * 4 + g;
      v[u] = r < e;
      int j = ssrc[v[u] ? r : s];
      p[u] = *reinterpret_cast<const uint2*>(hrp + (size_t)j * 64);
    }
#pragma unroll
    for (int u = 0; u < 4; ++u) {
      f32x2 A = unpk2(p[u].x);         // feats 0,1
      f32x2 B = unpk2(p[u].y);         // feats 2,3
      f32x2 z0 = xi01 + A;             // v_pk_add_f32
      f32x2 z1 = xi23 + B;
      z0 = __builtin_elementwise_max(z0, z0 * 0.2f);   // pk_mul + pk_max
      z1 = __builtin_elementwise_max(z1, z1 * 0.2f);
      f32x2 td = z0 * a01;                              // pk_mul
      td = __builtin_elementwise_fma(z1, a23, td);      // pk_fma
      float t = td.x + td.y;
      t += __shfl_xor(t, 1); t += __shfl_xor(t, 2);     // per-head dot (4 lanes)
      float ex = v[u] ? __expf(t) : 0.f;                // |score| << 88: no max-shift
      den += ex;
      f32x2 exv = ex;                                   // splat
      acc01 = __builtin_elementwise_fma(exv, A, acc01); // pk_fma
      acc23 = __builtin_elementwise_fma(exv, B, acc23);
    }
  }

  // reduce across the 4 edge slots
#pragma unroll
  for (int m = 16; m <= 32; m <<= 1) {
    den     += __shfl_xor(den, m);
    acc01.x += __shfl_xor(acc01.x, m);
    acc01.y += __shfl_xor(acc01.y, m);
    acc23.x += __shfl_xor(acc23.x, m);
    acc23.y += __shfl_xor(acc23.y, m);
  }

  if (g == 0) {
    float inv = (e > s) ? 1.f / den : 0.f;   // deg==0 -> bias only
    float4 b4 = *reinterpret_cast<const float4*>(bias + fo);
    float4 r;
    r.x = fmaf(acc01.x, inv, b4.x);
    r.y = fmaf(acc01.y, inv, b4.y);
    r.z = fmaf(acc23.x, inv, b4.z);
    r.w = fmaf(acc23.y, inv, b4.w);
    *reinterpret_cast<float4*>(out + (size_t)n * 64 + fo) = r;
  }
}

extern "C" void kernel_launch(void* const* d_in, const int* in_sizes, int n_in,
                              void* d_out, int out_size, void* d_ws, size_t ws_size,
                              hipStream_t stream) {
  const float* feat = (const float*)d_in[0];
  const int*   edge = (const int*)d_in[1];
  const float* wl   = (const float*)d_in[2];
  const float* wr   = (const float*)d_in[3];
  const float* att  = (const float*)d_in[4];
  const float* bias = (const float*)d_in[5];
  float* out = (float*)d_out;

  // workspace layout (~47.5 MB)
  float* hl       = (float*)d_ws;                        // NN*64 f32
  unsigned short* hrb = (unsigned short*)(hl + (size_t)NN * 64);  // NN*64 bf16
  int*   brec     = (int*)(hrb + (size_t)NN * 64);       // NB*BCAP (padded buckets)
  int*   bcursor  = brec + (size_t)NB * BCAP;            // NB*16 (padded, 1/line)
  int2*  srange   = (int2*)(bcursor + NB * 16);          // NN int2
  unsigned short* wt = (unsigned short*)(srange + NN);   // 16384 bf16

  const int nchunk = (NE + CHUNK - 1) / CHUNK;           // 391
  wprep_k<<<64, 256, 0, stream>>>(wl, wr, wt, bcursor);
  gemm_mfma<<<(NN + 127) / 128, 256, 0, stream>>>(feat, wt, hl, hrb);
  bscatter_k<<<nchunk, 256, 0, stream>>>(edge, bcursor, brec);
  bsort_k<<<NB, 256, 0, stream>>>(brec, bcursor, srange);
  node_k<<<NN / 4, 256, 0, stream>>>(hl, hrb, brec, srange, att, bias, out);
}

// Round 12
// 214.084 us; speedup vs baseline: 1.3873x; 1.0387x over previous
//
#include <hip/hip_runtime.h>

#define NN 100000
#define NE 1600000
#define NB 782          // ceil(NN/128) coarse buckets, 128 nodes each
#define CHUNK 4096
#define BCAP 2560       // padded bucket capacity (mean 2048, sigma ~45 -> 11 sigma)
#define LDP 136         // LDS row pitch in bf16 (128 + 8 pad -> 272B, 2-way free)

typedef __attribute__((ext_vector_type(8))) short bf16x8;
typedef __attribute__((ext_vector_type(4))) float f32x4;

static __device__ __forceinline__ unsigned short f2bf(float f) {
  unsigned int u = __float_as_uint(f);
  u += 0x7fff + ((u >> 16) & 1);       // round-to-nearest-even
  return (unsigned short)(u >> 16);
}

// One-time: wt[c][k] = bf16(W[k][c]) (c<64 -> W_l, c>=64 -> W_r) + bucket cursor init
__global__ void wprep_k(const float* __restrict__ wl, const float* __restrict__ wr,
                        unsigned short* __restrict__ wt, int* __restrict__ bcursor) {
  int i = blockIdx.x * 256 + threadIdx.x;     // 16384
  int c = i >> 7, k = i & 127;
  float v = (c < 64) ? wl[k * 64 + c] : wr[k * 64 + (c - 64)];
  wt[i] = f2bf(v);
  if (i < NB) bcursor[i * 16] = i * BCAP;     // padded-region base
}

// MFMA bf16 GEMM, 128-row tiles. A staged in LDS (coalesced feat reads, the
// r8-proven-necessary part); B fragments direct from the 16 KB L1/L2-resident
// wt table (staging B bought nothing). LDS 34.8 KB -> 4 blocks/CU.
__global__ __launch_bounds__(256) void gemm_mfma(const float* __restrict__ feat,
                                                 const unsigned short* __restrict__ wt,
                                                 float* __restrict__ hl,
                                                 unsigned short* __restrict__ hrb) {
  __shared__ unsigned short ldsA[128][LDP];   // feat tile, bf16 [row][k]
  const int tid = threadIdx.x;
  const int row0 = blockIdx.x * 128;

  for (int it = 0; it < 16; ++it) {
    int r = it * 8 + (tid >> 5);
    int gr = row0 + r;
    int k4 = (tid & 31) * 4;
    float4 v = make_float4(0.f, 0.f, 0.f, 0.f);
    if (gr < NN) v = *reinterpret_cast<const float4*>(&feat[(size_t)gr * 128 + k4]);
    union { unsigned short s[4]; uint2 u; } pk;
    pk.s[0] = f2bf(v.x); pk.s[1] = f2bf(v.y); pk.s[2] = f2bf(v.z); pk.s[3] = f2bf(v.w);
    *reinterpret_cast<uint2*>(&ldsA[r][k4]) = pk.u;
  }
  __syncthreads();

  const int w  = tid >> 6;
  const int ln = tid & 63;
  const int lr = ln & 15;
  const int kb = (ln >> 4) * 8;

  f32x4 acc[2][8];
#pragma unroll
  for (int mt = 0; mt < 2; ++mt)
#pragma unroll
    for (int nt = 0; nt < 8; ++nt) acc[mt][nt] = (f32x4){0.f, 0.f, 0.f, 0.f};

#pragma unroll
  for (int t = 0; t < 4; ++t) {
    const int ko = t * 32 + kb;
    bf16x8 af0 = *reinterpret_cast<const bf16x8*>(&ldsA[w * 32 + lr][ko]);
    bf16x8 af1 = *reinterpret_cast<const bf16x8*>(&ldsA[w * 32 + 16 + lr][ko]);
    bf16x8 bfr[8];
#pragma unroll
    for (int nt = 0; nt < 8; ++nt)
      bfr[nt] = *reinterpret_cast<const bf16x8*>(&wt[(size_t)(nt * 16 + lr) * 128 + ko]);
#pragma unroll
    for (int nt = 0; nt < 8; ++nt) {
      acc[0][nt] = __builtin_amdgcn_mfma_f32_16x16x32_bf16(af0, bfr[nt], acc[0][nt], 0, 0, 0);
      acc[1][nt] = __builtin_amdgcn_mfma_f32_16x16x32_bf16(af1, bfr[nt], acc[1][nt], 0, 0, 0);
    }
  }

#pragma unroll
  for (int mt = 0; mt < 2; ++mt) {
    int rrel = w * 32 + mt * 16 + (ln >> 4) * 4;
#pragma unroll
    for (int q = 0; q < 4; ++q) {
      int gr = row0 + rrel + q;
      if (gr < NN) {
#pragma unroll
        for (int nt = 0; nt < 4; ++nt)       // cols 0..63 -> h_l (f32)
          hl[(size_t)gr * 64 + nt * 16 + lr] = acc[mt][nt][q];
#pragma unroll
        for (int nt = 4; nt < 8; ++nt)       // cols 64..127 -> h_r (bf16)
          hrb[(size_t)gr * 64 + (nt - 4) * 16 + lr] = f2bf(acc[mt][nt][q]);
      }
    }
  }
}

// Bucket-partition edges into fixed padded regions (bucket b owns
// [b*BCAP, (b+1)*BCAP)). 512 threads: halved serial stride loops.
// LDS-staged writeout. rec = (src<<7)|tgt_local.
__global__ __launch_bounds__(512) void bscatter_k(const int* __restrict__ edge,
                                                  int* __restrict__ bcursor,
                                                  int* __restrict__ brec) {
  __shared__ int lcnt[NB];
  __shared__ int lstart[NB];
  __shared__ int gbase[NB];
  __shared__ int lcur[NB];
  __shared__ int srec[CHUNK];
  __shared__ unsigned short bid[CHUNK];
  __shared__ int sd[512];
  const int tid = threadIdx.x;
  const int base = blockIdx.x * CHUNK;
  const int lim = min(CHUNK, NE - base);

  for (int b = tid; b < NB; b += 512) { lcnt[b] = 0; lcur[b] = 0; }
  __syncthreads();
  for (int i = tid; i < lim; i += 512)
    atomicAdd(&lcnt[edge[NE + base + i] >> 7], 1);
  __syncthreads();

  // 512-thread scan, 2 elems/thread
  int v[2]; int s = 0;
#pragma unroll
  for (int j = 0; j < 2; ++j) {
    int idx = tid * 2 + j;
    v[j] = (idx < NB) ? lcnt[idx] : 0;
    s += v[j];
  }
  sd[tid] = s;
  __syncthreads();
  for (int off = 1; off < 512; off <<= 1) {
    int t = (tid >= off) ? sd[tid - off] : 0;
    __syncthreads();
    sd[tid] += t;
    __syncthreads();
  }
  int run = sd[tid] - s;
#pragma unroll
  for (int j = 0; j < 2; ++j) {
    int idx = tid * 2 + j;
    if (idx < NB) lstart[idx] = run;
    run += v[j];
  }
  __syncthreads();

  for (int b = tid; b < NB; b += 512)
    if (lcnt[b] > 0) gbase[b] = atomicAdd(&bcursor[b * 16], lcnt[b]);
  __syncthreads();

  for (int i = tid; i < lim; i += 512) {
    int tg = edge[NE + base + i];
    int sr = edge[base + i];
    int b = tg >> 7;
    int r = atomicAdd(&lcur[b], 1);
    int slot = lstart[b] + r;
    srec[slot] = (sr << 7) | (tg & 127);
    bid[slot] = (unsigned short)b;
  }
  __syncthreads();

  for (int i = tid; i < lim; i += 512) {
    int b = bid[i];
    brec[gbase[b] + i - lstart[b]] = srec[i];
  }
}

// Node-level sort within each padded bucket; emits absolute (start,end) per node.
// 512 threads: halved stride loops over the ~2048-record bucket.
__global__ __launch_bounds__(512) void bsort_k(int* __restrict__ brec,
                                               const int* __restrict__ bcursor,
                                               int2* __restrict__ srange) {
  __shared__ int srec[BCAP];
  __shared__ int ncnt[128];
  __shared__ int nst[128];
  __shared__ int sd2[128];
  const int tid = threadIdx.x;
  const int b = blockIdx.x;
  const int s0 = b * BCAP;
  const int cnt = bcursor[b * 16] - s0;

  if (tid < 128) ncnt[tid] = 0;
  __syncthreads();
  for (int i = tid; i < cnt; i += 512) {
    int r = brec[s0 + i];
    srec[i] = r;
    atomicAdd(&ncnt[r & 127], 1);
  }
  __syncthreads();

  int val = (tid < 128) ? ncnt[tid] : 0;
  if (tid < 128) sd2[tid] = val;
  __syncthreads();
  for (int off = 1; off < 128; off <<= 1) {
    int t = 0;
    if (tid < 128 && tid >= off) t = sd2[tid - off];
    __syncthreads();
    if (tid < 128) sd2[tid] += t;
    __syncthreads();
  }
  if (tid < 128) {
    int st = sd2[tid] - val;
    nst[tid] = st;
    int nid = (b << 7) + tid;
    if (nid < NN) srange[nid] = make_int2(s0 + st, s0 + st + val);
    ncnt[tid] = 0;                       // reuse as cursor
  }
  __syncthreads();

  for (int i = tid; i < cnt; i += 512) {
    int r = srec[i];
    int tl = r & 127;
    int p = atomicAdd(&ncnt[tl], 1);
    brec[s0 + nst[tl] + p] = r >> 7;     // final: grouped src ids
  }
}

#define UNPK(D_, U0_, U1_)                             \
  D_.x = __uint_as_float((U0_) << 16);                 \
  D_.y = __uint_as_float((U0_) & 0xffff0000u);         \
  D_.z = __uint_as_float((U1_) << 16);                 \
  D_.w = __uint_as_float((U1_) & 0xffff0000u);

#define ACC(AC_, E_, X_)                               \
  AC_.x = fmaf(E_, X_.x, AC_.x); AC_.y = fmaf(E_, X_.y, AC_.y); \
  AC_.z = fmaf(E_, X_.z, AC_.z); AC_.w = fmaf(E_, X_.w, AC_.w);

// One wave per node; 16 lanes per edge (4 heads x float4), 16 edges in flight
// (r10 proven best: 52.5 us). h_r gathered as bf16.
__global__ __launch_bounds__(256) void node_k(const float* __restrict__ hl,
                                              const unsigned short* __restrict__ hrb,
                                              const int* __restrict__ ssrc,
                                              const int2* __restrict__ srange,
                                              const float* __restrict__ att,
                                              const float* __restrict__ bias,
                                              float* __restrict__ out) {
  const int lane = threadIdx.x & 63;
  const int n  = blockIdx.x * 4 + (threadIdx.x >> 6);
  const int g  = lane >> 4;          // edge slot 0..3
  const int fo = (lane & 15) * 4;    // (head,feature-quad) offset within 64

  const float4 xi = *reinterpret_cast<const float4*>(hl + (size_t)n * 64 + fo);
  const float4 a  = *reinterpret_cast<const float4*>(att + fo);
  const int2 se = srange[n];
  const int s = se.x, e = se.y;
  const unsigned short* __restrict__ hrp = hrb + fo;

  float  den = 0.f;
  float4 acc = make_float4(0.f, 0.f, 0.f, 0.f);

  for (int i = s; i < e; i += 16) {
    uint2 p[4];
    bool  v[4];
#pragma unroll
    for (int u = 0; u < 4; ++u) {      // 4 independent gathers in flight
      int r = i + u * 4 + g;
      v[u] = r < e;
      int j = ssrc[v[u] ? r : s];
      p[u] = *reinterpret_cast<const uint2*>(hrp + (size_t)j * 64);
    }
#pragma unroll
    for (int u = 0; u < 4; ++u) {
      float4 x;
      UNPK(x, p[u].x, p[u].y);
      float4 z;
      z.x = xi.x + x.x; z.y = xi.y + x.y; z.z = xi.z + x.z; z.w = xi.w + x.w;
      z.x = fmaxf(z.x, 0.2f * z.x); z.y = fmaxf(z.y, 0.2f * z.y);
      z.z = fmaxf(z.z, 0.2f * z.z); z.w = fmaxf(z.w, 0.2f * z.w);
      float t = z.x * a.x;
      t = fmaf(z.y, a.y, t); t = fmaf(z.z, a.z, t); t = fmaf(z.w, a.w, t);
      t += __shfl_xor(t, 1); t += __shfl_xor(t, 2);   // per-head dot (4 lanes)
      float ex = v[u] ? __expf(t) : 0.f;              // |score| << 88: no max-shift
      den += ex;
      ACC(acc, ex, x);
    }
  }

  // reduce across the 4 edge slots
#pragma unroll
  for (int m = 16; m <= 32; m <<= 1) {
    den   += __shfl_xor(den, m);
    acc.x += __shfl_xor(acc.x, m);
    acc.y += __shfl_xor(acc.y, m);
    acc.z += __shfl_xor(acc.z, m);
    acc.w += __shfl_xor(acc.w, m);
  }

  if (g == 0) {
    float inv = (e > s) ? 1.f / den : 0.f;   // deg==0 -> bias only
    float4 b4 = *reinterpret_cast<const float4*>(bias + fo);
    float4 r;
    r.x = fmaf(acc.x, inv, b4.x);
    r.y = fmaf(acc.y, inv, b4.y);
    r.z = fmaf(acc.z, inv, b4.z);
    r.w = fmaf(acc.w, inv, b4.w);
    *reinterpret_cast<float4*>(out + (size_t)n * 64 + fo) = r;
  }
}

extern "C" void kernel_launch(void* const* d_in, const int* in_sizes, int n_in,
                              void* d_out, int out_size, void* d_ws, size_t ws_size,
                              hipStream_t stream) {
  const float* feat = (const float*)d_in[0];
  const int*   edge = (const int*)d_in[1];
  const float* wl   = (const float*)d_in[2];
  const float* wr   = (const float*)d_in[3];
  const float* att  = (const float*)d_in[4];
  const float* bias = (const float*)d_in[5];
  float* out = (float*)d_out;

  // workspace layout (~47.5 MB)
  float* hl       = (float*)d_ws;                        // NN*64 f32
  unsigned short* hrb = (unsigned short*)(hl + (size_t)NN * 64);  // NN*64 bf16
  int*   brec     = (int*)(hrb + (size_t)NN * 64);       // NB*BCAP (padded buckets)
  int*   bcursor  = brec + (size_t)NB * BCAP;            // NB*16 (padded, 1/line)
  int2*  srange   = (int2*)(bcursor + NB * 16);          // NN int2
  unsigned short* wt = (unsigned short*)(srange + NN);   // 16384 bf16

  const int nchunk = (NE + CHUNK - 1) / CHUNK;           // 391
  wprep_k<<<64, 256, 0, stream>>>(wl, wr, wt, bcursor);
  gemm_mfma<<<(NN + 127) / 128, 256, 0, stream>>>(feat, wt, hl, hrb);
  bscatter_k<<<nchunk, 512, 0, stream>>>(edge, bcursor, brec);
  bsort_k<<<NB, 512, 0, stream>>>(brec, bcursor, srange);
  node_k<<<NN / 4, 256, 0, stream>>>(hl, hrb, brec, srange, att, bias, out);
}